// Round 4
// baseline (970.264 us; speedup 1.0000x reference)
//
#include <hip/hip_runtime.h>
#include <hip/hip_bf16.h>

// Problem constants
#define HH 180      // hidden / feature size
#define TT 240      // timesteps
#define KP 192      // K padded to 6*32 for MFMA
#define MP 576      // 3 gate sections (i,g,o) x 192 rows
#define KOUT 43200  // T*H
#define BB 2048

// phaseA tiling
#define NCOL 80     // t-columns per block (3 chunks x 80 = 240, zero overlap)
#define KD 96       // dwords per column (192 bf16), XOR-swizzled
#define NW 12       // waves per block (wave w owns gate-row triplet tri=w)
#define ATHR 768    // NW*64

typedef __attribute__((ext_vector_type(8))) short short8;
typedef __attribute__((ext_vector_type(4))) float float4v;

__device__ inline unsigned short f2bf(float f) {
    unsigned u = __builtin_bit_cast(unsigned, f);
    u += 0x7fffu + ((u >> 16) & 1u);          // round-to-nearest-even
    return (unsigned short)(u >> 16);
}
// HW packed f32x2 -> bf16x2 (v_cvt_pk_bf16_f32), RNE.
__device__ inline unsigned pack_bf2(float a, float b) {
    union { __hip_bfloat162 h; unsigned u; } t;
    t.h = __float22bfloat162_rn(make_float2(a, b));
    return t.u;
}

// Fused LSTM activation: given pa=e^{-gi}, pb=e^{-2*gg}, po=e^{-go},
// returns hv = sigmoid(gi)*tanh(gg) -> cc; sigmoid(go)*tanh(cc).
// tanh(cc) for |cc|<1 via Pade(5,4) (err < 1e-7 on [-1,1]); its divide
// merges with sigmoid(go)'s into ONE rcp. Total: 2 rcp (vs 4 sigm/tanh rcp
// + the rcp-per-trans of the naive form).
__device__ inline float lstm_act(float pa, float pb, float po) {
    float cc  = (1.f - pb) * __builtin_amdgcn_rcpf((1.f + pa) * (1.f + pb));
    float x2  = cc * cc;
    float num = cc * (x2 * (x2 + 105.f) + 945.f);
    float den = x2 * (x2 * 15.f + 420.f) + 945.f;
    return num * __builtin_amdgcn_rcpf(den * (1.f + po));
}

// ---------------------------------------------------------------------------
// prep: build reordered/padded bf16 weights + fused biases + zero logits.
// W'[g*192+h][k] = W[(g==0?h:g==1?360+h:540+h)][k]  (i,g,o sections; f-gate dead)
// ---------------------------------------------------------------------------
__global__ void prep_kernel(const float* __restrict__ W1, const float* __restrict__ bi1,
                            const float* __restrict__ bh1, const float* __restrict__ W2,
                            const float* __restrict__ bi2, const float* __restrict__ bh2,
                            const float* __restrict__ Wo,
                            unsigned short* __restrict__ W1p, unsigned short* __restrict__ W2p,
                            float* __restrict__ bEp, float* __restrict__ bDp,
                            unsigned short* __restrict__ Wop, float* __restrict__ logits)
{
    int id = blockIdx.x * 256 + threadIdx.x;
    if (id < MP * KP) {
        int mp = id / KP, k = id % KP;
        int g = mp / KP, h = mp % KP;   // note MP/3 == KP == 192
        unsigned short v1 = 0, v2 = 0;
        if (h < HH && k < HH) {
            int r = (g == 0) ? h : (g == 1 ? 360 + h : 540 + h);
            v1 = f2bf(W1[r * HH + k]);
            v2 = f2bf(W2[r * HH + k]);
        }
        W1p[id] = v1; W2p[id] = v2;
    }
    if (id < MP) {
        int g = id / KP, h = id % KP;
        float v1 = 0.f, v2 = 0.f;
        if (h < HH) {
            int r = (g == 0) ? h : (g == 1 ? 360 + h : 540 + h);
            v1 = bi1[r] + bh1[r];
            v2 = bi2[r] + bh2[r];
        }
        bEp[id] = v1; bDp[id] = v2;
    }
    if (id < 48 * KOUT) {
        int n = id / KOUT, k = id % KOUT;
        Wop[id] = (n < 40) ? f2bf(Wo[n * KOUT + k]) : (unsigned short)0;
    }
    if (id < BB * 40) logits[id] = 0.f;
}

// ---------------------------------------------------------------------------
// phaseA (v4): A-stationary fused enc GEMM -> gates -> exp -> dec GEMM -> hdec.
// Grid (3, BB): chunk = blockIdx.x, t0 = 80*chunk -> 240 cols exact, NO overlap
// (v3 wasted 6.7% on duplicated cols). 12 waves; wave w holds W-row triplet
// tri=w in 72 VGPRs loaded once per GEMM from L2.
// Epilogue math rebuilt for trans-op count (the VALU-pipe hog per R2 counters):
// 9 -> 6 trans/elem in GEMM1 (4 exp + 2 rcp), 8 -> 5 in GEMM2, via fused
// sigmoid/tanh denominators + Pade(5,4) tanh on the bounded cc argument.
// exp args are single FMAs against pre-negated/pre-doubled biases.
// ---------------------------------------------------------------------------
__global__ __launch_bounds__(ATHR, 3) void phaseA_kernel(
    const float* __restrict__ x, const unsigned short* __restrict__ W1p,
    const unsigned short* __restrict__ W2p, const float* __restrict__ bEp,
    const float* __restrict__ bDp, unsigned short* __restrict__ hdec)
{
    __shared__ __align__(16) unsigned XsD[NCOL * KD];   // x tile bf16x2, 30720 B
    __shared__ __align__(16) unsigned EsD[NCOL * KD];   // E tile bf16x2, 30720 B
    __shared__ float bEs[MP], bDs[MP];                  //  4608 B
    __shared__ float sred2[NCOL];                       //   320 B

    const int tid = threadIdx.x;
    const int b = blockIdx.y;
    const int t0 = blockIdx.x * NCOL;
    const float* xb = x + (size_t)b * HH * TT;

    for (int i = tid; i < MP; i += ATHR) { bEs[i] = bEp[i]; bDs[i] = bDp[i]; }
    if (tid < NCOL) sred2[tid] = 0.f;

    // ---- stage x[b][:, t0:t0+80] as bf16 into XsD (swizzled) ---------------
    // i = p*80 + c: consecutive tid -> consecutive c -> coalesced global loads.
    #pragma unroll
    for (int it = 0; it < 10; ++it) {
        int i = it * ATHR + tid;                        // 0..7679
        int p = i / NCOL;                               // dword 0..95
        int c = i - p * NCOL;                           // col 0..79
        unsigned v = 0u;
        if (p < 90) {
            float a0 = xb[(size_t)(2 * p) * TT + t0 + c];
            float a1 = xb[(size_t)(2 * p + 1) * TT + t0 + c];
            v = pack_bf2(a0, a1);
        }
        XsD[(c * KD + p) ^ ((c & 7) << 2)] = v;         // p>=90: zero k-pad
    }

    const int lane = tid & 63, wv = tid >> 6;           // wv = tri owner 0..11
    const int l15 = lane & 15, l4 = lane >> 4;
    const int h0 = wv * 16 + l4 * 4;                    // 4 h-rows this lane owns

    // ---- A1 (W1') fragments -> registers, overlaps staging-barrier wait ----
    const uint4* W1q = (const uint4*)W1p;
    const uint4* W2q = (const uint4*)W2p;
    short8 Af[3][6];
    #pragma unroll
    for (int sec = 0; sec < 3; ++sec) {
        int rowbase = (sec * KP + wv * 16 + l15) * (KP / 8) + l4;
        #pragma unroll
        for (int ks = 0; ks < 6; ++ks) {
            union { uint4 q; short8 v; } a;
            a.q = W1q[rowbase + ks * 4];
            Af[sec][ks] = a.v;
        }
    }
    __syncthreads();

    // pre-negated / pre-doubled gate biases for single-FMA exp args
    float nbi[4], nbg[4], nbo[4];
    #pragma unroll
    for (int e = 0; e < 4; ++e) {
        nbi[e] = -bEs[h0 + e];
        nbg[e] = -2.f * bEs[KP + h0 + e];
        nbo[e] = -bEs[2 * KP + h0 + e];
    }

    // ---- GEMM1: 5 coltiles of 16; epilogue -> E in EsD + denom atomics -----
    #pragma unroll 1
    for (int ct = 0; ct < 5; ++ct) {
        const int col = ct * 16 + l15;
        const int swz = (col & 7) << 2;
        const int bb = col * KD + l4 * 4;
        short8 Bf[6];
        #pragma unroll
        for (int ks = 0; ks < 6; ++ks) {
            union { uint4 q; short8 v; } t;
            t.q = *(const uint4*)&XsD[(bb + ks * 16) ^ swz];
            Bf[ks] = t.v;
        }
        float4v acc[3];
        acc[0] = (float4v){0.f, 0.f, 0.f, 0.f};
        acc[1] = (float4v){0.f, 0.f, 0.f, 0.f};
        acc[2] = (float4v){0.f, 0.f, 0.f, 0.f};
        #pragma unroll
        for (int ks = 0; ks < 6; ++ks) {
            acc[0] = __builtin_amdgcn_mfma_f32_16x16x32_bf16(Af[0][ks], Bf[ks], acc[0], 0, 0, 0);
            acc[1] = __builtin_amdgcn_mfma_f32_16x16x32_bf16(Af[1][ks], Bf[ks], acc[1], 0, 0, 0);
            acc[2] = __builtin_amdgcn_mfma_f32_16x16x32_bf16(Af[2][ks], Bf[ks], acc[2], 0, 0, 0);
        }
        float ev[4], es = 0.f;
        #pragma unroll
        for (int e = 0; e < 4; ++e) {
            float pa = __expf(fmaf(acc[0][e], -1.f, nbi[e]));   // e^{-gi}
            float pb = __expf(fmaf(acc[1][e], -2.f, nbg[e]));   // e^{-2gg}
            float po = __expf(fmaf(acc[2][e], -1.f, nbo[e]));   // e^{-go}
            float hv = lstm_act(pa, pb, po);
            ev[e] = __expf(hv);
            es += (h0 + e < HH) ? ev[e] : 0.f;   // exclude pad rows (E=1 there)
        }
        // pad rows 180..191 still written: gates=0 -> E=1; W2' k-cols >=180
        // are zero -> harmless.
        {
            int kd = (col * KD + (h0 >> 1)) ^ swz;   // kd even; swz bits >=2
            uint2 pv;
            pv.x = pack_bf2(ev[0], ev[1]);
            pv.y = pack_bf2(ev[2], ev[3]);
            *(uint2*)&EsD[kd] = pv;
        }
        es += __shfl_xor(es, 16);
        es += __shfl_xor(es, 32);
        if (lane < 16) atomicAdd(&sred2[ct * 16 + lane], es);
    }

    // ---- A2 (W2') fragments -> same registers; overlaps barrier wait -------
    #pragma unroll
    for (int sec = 0; sec < 3; ++sec) {
        int rowbase = (sec * KP + wv * 16 + l15) * (KP / 8) + l4;
        #pragma unroll
        for (int ks = 0; ks < 6; ++ks) {
            union { uint4 q; short8 v; } a;
            a.q = W2q[rowbase + ks * 4];
            Af[sec][ks] = a.v;
        }
    }
    __syncthreads();   // EsD + sred2 complete

    #pragma unroll
    for (int e = 0; e < 4; ++e) {
        nbi[e] = -bDs[h0 + e];
        nbg[e] = -2.f * bDs[KP + h0 + e];
        nbo[e] = -bDs[2 * KP + h0 + e];
    }

    // ---- GEMM2: gates2 = (W2' @ E) * (1/sum) + b -> h_dec (global) ---------
    unsigned short* hout = hdec + (size_t)b * TT * HH;
    #pragma unroll 1
    for (int ct = 0; ct < 5; ++ct) {
        const int col = ct * 16 + l15;
        const int swz = (col & 7) << 2;
        const int bb = col * KD + l4 * 4;
        short8 Bf[6];
        #pragma unroll
        for (int ks = 0; ks < 6; ++ks) {
            union { uint4 q; short8 v; } t;
            t.q = *(const uint4*)&EsD[(bb + ks * 16) ^ swz];
            Bf[ks] = t.v;
        }
        float4v acc[3];
        acc[0] = (float4v){0.f, 0.f, 0.f, 0.f};
        acc[1] = (float4v){0.f, 0.f, 0.f, 0.f};
        acc[2] = (float4v){0.f, 0.f, 0.f, 0.f};
        #pragma unroll
        for (int ks = 0; ks < 6; ++ks) {
            acc[0] = __builtin_amdgcn_mfma_f32_16x16x32_bf16(Af[0][ks], Bf[ks], acc[0], 0, 0, 0);
            acc[1] = __builtin_amdgcn_mfma_f32_16x16x32_bf16(Af[1][ks], Bf[ks], acc[1], 0, 0, 0);
            acc[2] = __builtin_amdgcn_mfma_f32_16x16x32_bf16(Af[2][ks], Bf[ks], acc[2], 0, 0, 0);
        }
        if (h0 < HH) {                          // skip pad quads (wv==11, l4>0)
            float nrs  = -__builtin_amdgcn_rcpf(sred2[col]);   // -1/sum
            float nrs2 = nrs + nrs;
            float o[4];
            #pragma unroll
            for (int e = 0; e < 4; ++e) {
                float pa = __expf(fmaf(acc[0][e], nrs,  nbi[e]));  // e^{-gi}
                float pb = __expf(fmaf(acc[1][e], nrs2, nbg[e]));  // e^{-2gg}
                float po = __expf(fmaf(acc[2][e], nrs,  nbo[e]));  // e^{-go}
                o[e] = lstm_act(pa, pb, po);
            }
            uint2 pv;
            pv.x = pack_bf2(o[0], o[1]);
            pv.y = pack_bf2(o[2], o[3]);
            *(uint2*)(hout + (size_t)(t0 + col) * HH + h0) = pv;
        }
    }
}

// ---------------------------------------------------------------------------
// phaseB: logits += hdec[2048 x 43200] @ Wo'^T[43200 x 48] (K-split, atomics)
// grid (32 M-blocks, 30 K-chunks of 1440); block 4 waves x 16 rows x 48 cols.
// ---------------------------------------------------------------------------
__global__ __launch_bounds__(256, 4) void phaseB_kernel(
    const unsigned short* __restrict__ hdec, const unsigned short* __restrict__ Wop,
    float* __restrict__ logits)
{
    const int tid = threadIdx.x;
    const int lane = tid & 63, wv = tid >> 6;
    const int l15 = lane & 15, l4 = lane >> 4;
    const int m0 = blockIdx.x * 64 + wv * 16;
    const int k0 = blockIdx.y * 1440;

    const uint4* Aq = (const uint4*)hdec;
    const uint4* Bq = (const uint4*)Wop;
    const int QK = KOUT / 8;                     // 5400 uint4 per row
    int abase = (m0 + l15) * QK + (k0 >> 3) + l4;
    int bbase = l15 * QK + (k0 >> 3) + l4;

    float4v acc[3];
    #pragma unroll
    for (int n = 0; n < 3; ++n) acc[n] = (float4v){0.f, 0.f, 0.f, 0.f};

    #pragma unroll 5
    for (int ks = 0; ks < 45; ++ks) {
        union { uint4 q; short8 v; } a, b0, b1, b2;
        a.q  = Aq[abase + ks * 4];
        b0.q = Bq[bbase + ks * 4];
        b1.q = Bq[bbase + 16 * QK + ks * 4];
        b2.q = Bq[bbase + 32 * QK + ks * 4];
        acc[0] = __builtin_amdgcn_mfma_f32_16x16x32_bf16(a.v, b0.v, acc[0], 0, 0, 0);
        acc[1] = __builtin_amdgcn_mfma_f32_16x16x32_bf16(a.v, b1.v, acc[1], 0, 0, 0);
        acc[2] = __builtin_amdgcn_mfma_f32_16x16x32_bf16(a.v, b2.v, acc[2], 0, 0, 0);
    }

    #pragma unroll
    for (int nt = 0; nt < 3; ++nt) {
        int o = nt * 16 + l15;
        if (o < 40) {
            #pragma unroll
            for (int e = 0; e < 4; ++e) {
                int row = m0 + l4 * 4 + e;
                atomicAdd(&logits[row * 40 + o], acc[nt][e]);
            }
        }
    }
}

// ---------------------------------------------------------------------------
// outK: out[b][j][:] = softmax(logits[b][10j..10j+9] + b_out)
// ---------------------------------------------------------------------------
__global__ void out_kernel(const float* __restrict__ logits, const float* __restrict__ bout,
                           float* __restrict__ out)
{
    int id = blockIdx.x * 256 + threadIdx.x;
    if (id >= BB * 4) return;
    int b = id >> 2, j = id & 3;
    float v[10], mx = -1e30f;
    #pragma unroll
    for (int d = 0; d < 10; ++d) {
        v[d] = logits[b * 40 + j * 10 + d] + bout[j * 10 + d];
        mx = fmaxf(mx, v[d]);
    }
    float s = 0.f;
    #pragma unroll
    for (int d = 0; d < 10; ++d) { v[d] = __expf(v[d] - mx); s += v[d]; }
    float r = __builtin_amdgcn_rcpf(s);
    #pragma unroll
    for (int d = 0; d < 10; ++d) out[b * 40 + j * 10 + d] = v[d] * r;
}

// ---------------------------------------------------------------------------
extern "C" void kernel_launch(void* const* d_in, const int* in_sizes, int n_in,
                              void* d_out, int out_size, void* d_ws, size_t ws_size,
                              hipStream_t stream)
{
    const float* x    = (const float*)d_in[0];
    const float* W1   = (const float*)d_in[1];
    const float* bi1  = (const float*)d_in[2];
    const float* bh1  = (const float*)d_in[3];
    const float* W2   = (const float*)d_in[4];
    const float* bi2  = (const float*)d_in[5];
    const float* bh2  = (const float*)d_in[6];
    const float* Wo   = (const float*)d_in[7];
    const float* bout = (const float*)d_in[8];

    // workspace carve (all offsets 512B-aligned); total ~173.5 MiB
    char* ws = (char*)d_ws;
    unsigned short* W1p = (unsigned short*)(ws + 0);          // 576*192*2 = 221184
    unsigned short* W2p = (unsigned short*)(ws + 221184);     // 221184
    float* bEp          = (float*)(ws + 442368);              // 2304 (+pad)
    float* bDp          = (float*)(ws + 444928);              // 2304 (+pad)
    unsigned short* Wop = (unsigned short*)(ws + 447488);     // 48*43200*2 = 4147200
    float* logits       = (float*)(ws + 4594688);             // 2048*40*4 = 327680
    unsigned short* hdec= (unsigned short*)(ws + 4922368);    // 2048*240*180*2

    prep_kernel<<<(48 * KOUT + 255) / 256, 256, 0, stream>>>(
        W1, bi1, bh1, W2, bi2, bh2, Wo, W1p, W2p, bEp, bDp, Wop, logits);
    phaseA_kernel<<<dim3(3, BB), ATHR, 0, stream>>>(x, W1p, W2p, bEp, bDp, hdec);
    phaseB_kernel<<<dim3(32, 30), 256, 0, stream>>>(hdec, Wop, logits);
    out_kernel<<<(BB * 4 + 255) / 256, 256, 0, stream>>>(logits, bout, (float*)d_out);
}